// Round 1
// baseline (73.315 us; speedup 1.0000x reference)
//
#include <hip/hip_runtime.h>

#define N_BINS 30
#define NCLASS 10

// Workspace layout (all in d_ws):
//   [0]   : 30 x unsigned long long  sum_conf fixed-point (conf * 2^32)
//   [240] : 30 x unsigned int        counts
//   [360] : 30 x unsigned int        correct
// (d_ws is poisoned 0xAA and never re-poisoned -> we zero it every call.)

__global__ void ece_zero_ws(unsigned long long* sum_conf,
                            unsigned int* counts,
                            unsigned int* correct) {
    int i = threadIdx.x;
    if (i < N_BINS) {
        sum_conf[i] = 0ull;
        counts[i]   = 0u;
        correct[i]  = 0u;
    }
}

__global__ __launch_bounds__(256) void ece_hist(
        const float* __restrict__ sm,
        const int*   __restrict__ labels,
        int n,
        unsigned long long* __restrict__ g_sumconf,
        unsigned int* __restrict__ g_counts,
        unsigned int* __restrict__ g_correct) {
    __shared__ unsigned long long s_sumconf[N_BINS];
    __shared__ unsigned int s_counts[N_BINS];
    __shared__ unsigned int s_correct[N_BINS];

    for (int i = threadIdx.x; i < N_BINS; i += blockDim.x) {
        s_sumconf[i] = 0ull;
        s_counts[i]  = 0u;
        s_correct[i] = 0u;
    }
    __syncthreads();

    const long long stride = (long long)gridDim.x * blockDim.x;
    for (long long r = (long long)blockIdx.x * blockDim.x + threadIdx.x;
         r < n; r += stride) {
        const float* row = sm + r * NCLASS;
        // 40-byte rows are 8B-aligned: 5 x float2
        float2 v0 = *reinterpret_cast<const float2*>(row + 0);
        float2 v1 = *reinterpret_cast<const float2*>(row + 2);
        float2 v2 = *reinterpret_cast<const float2*>(row + 4);
        float2 v3 = *reinterpret_cast<const float2*>(row + 6);
        float2 v4 = *reinterpret_cast<const float2*>(row + 8);

        float v[NCLASS] = {v0.x, v0.y, v1.x, v1.y, v2.x,
                           v2.y, v3.x, v3.y, v4.x, v4.y};

        // argmax with first-occurrence tie-break (strict >)
        float conf = v[0];
        int pred = 0;
        #pragma unroll
        for (int j = 1; j < NCLASS; ++j) {
            if (v[j] > conf) { conf = v[j]; pred = j; }
        }

        int lbl = labels[r];
        unsigned int acc = (pred == lbl) ? 1u : 0u;

        int bin = (int)ceilf(conf * (float)N_BINS) - 1;
        bin = min(max(bin, 0), N_BINS - 1);

        // exact fixed-point: conf * 2^32 (power-of-two scale, no rounding)
        unsigned long long fx = (unsigned long long)((double)conf * 4294967296.0);

        atomicAdd(&s_sumconf[bin], fx);
        atomicAdd(&s_counts[bin], 1u);
        atomicAdd(&s_correct[bin], acc);
    }
    __syncthreads();

    for (int i = threadIdx.x; i < N_BINS; i += blockDim.x) {
        if (s_counts[i]) {
            atomicAdd(&g_sumconf[i], s_sumconf[i]);
            atomicAdd(&g_counts[i],  s_counts[i]);
            atomicAdd(&g_correct[i], s_correct[i]);
        }
    }
}

__global__ void ece_final(const unsigned long long* __restrict__ sum_conf,
                          const unsigned int* __restrict__ counts,
                          const unsigned int* __restrict__ correct,
                          float* __restrict__ out,
                          float n_total) {
    if (blockIdx.x == 0 && threadIdx.x == 0) {
        float ece = 0.0f;
        for (int b = 0; b < N_BINS; ++b) {
            unsigned int cnt = counts[b];
            if (cnt > 0u) {
                float fcnt = (float)cnt;
                float avg_conf = (float)((double)sum_conf[b] / 4294967296.0) / fcnt;
                float acc_in_bin = (float)correct[b] / fcnt;
                float prop = fcnt / n_total;
                ece += fabsf(avg_conf - acc_in_bin) * prop;
            }
        }
        out[0] = ece;
    }
}

extern "C" void kernel_launch(void* const* d_in, const int* in_sizes, int n_in,
                              void* d_out, int out_size, void* d_ws, size_t ws_size,
                              hipStream_t stream) {
    const float* sm  = (const float*)d_in[0];
    const int* labels = (const int*)d_in[1];
    const int n = in_sizes[1];   // 4,000,000 rows (labels count)

    unsigned long long* g_sumconf = (unsigned long long*)d_ws;
    unsigned int* g_counts  = (unsigned int*)((char*)d_ws + N_BINS * sizeof(unsigned long long));
    unsigned int* g_correct = g_counts + N_BINS;

    ece_zero_ws<<<1, 64, 0, stream>>>(g_sumconf, g_counts, g_correct);

    const int block = 256;
    const int grid = 2048;   // grid-stride; ~7.6 rows/thread
    ece_hist<<<grid, block, 0, stream>>>(sm, labels, n, g_sumconf, g_counts, g_correct);

    ece_final<<<1, 64, 0, stream>>>(g_sumconf, g_counts, g_correct,
                                    (float*)d_out, (float)n);
}